// Round 3
// baseline (1005.954 us; speedup 1.0000x reference)
//
#include <hip/hip_runtime.h>
#include <hip/hip_bf16.h>
#include <math.h>

// Transformer block: rmsnorm -> fused QK GEMM + V^T GEMM -> rope -> causal flash attn
// (v3: no LDS staging of K/V, no barriers) -> Wo + residual -> rmsnorm -> SwiGLU MLP
// -> split-K down-proj + residual.  fp32 in/out; bf16 internal compute.

#define HIDDENC 2048
#define SLEN    2048
#define NHEADS  16
#define NKV     4
#define HD      128
#define INTERC  8192

typedef __attribute__((ext_vector_type(8))) short bf16x8;   // 8 x bf16 (4 VGPRs)
typedef __attribute__((ext_vector_type(4))) float f32x4;
typedef __hip_bfloat16 bf16;

__device__ __forceinline__ void gld_lds16(const void* g, void* l) {
    __builtin_amdgcn_global_load_lds((const __attribute__((address_space(1))) void*)g,
                                     (__attribute__((address_space(3))) void*)l, 16, 0, 0);
}

__device__ __forceinline__ unsigned short bf_bits(float x) {
    bf16 t = __float2bfloat16(x);
    return *(unsigned short*)&t;
}
__device__ __forceinline__ float bits_f(short s) {
    bf16 b = *(bf16*)&s;
    return __bfloat162float(b);
}

// ---------------- GEMM: C[M][N] = A[M][K'] @ B[N][K']^T, row stride lda -------------
// EPI=0: bf16 C.  EPI=1: fp32 C = acc + R.  EPI=2: fp32 partial at Cout + z*M*N.
template <int EPI>
__global__ __launch_bounds__(256) void gemm_bt(const bf16* __restrict__ A,
                                               const bf16* __restrict__ B,
                                               void* __restrict__ Cout,
                                               const float* __restrict__ R,
                                               int M, int N, int K, int lda) {
    constexpr int BM = 128, BN = 128, BK = 64;
    __shared__ bf16 As[BM * BK];
    __shared__ bf16 Bs[BN * BK];
    const int tid  = threadIdx.x;
    const int wave = tid >> 6;
    const int lane = tid & 63;
    const int wm = wave >> 1, wn = wave & 1;        // 2x2 waves, 64x64 each
    const long m0 = (long)blockIdx.y * BM;
    const long n0 = (long)blockIdx.x * BN;
    const long kofs = (long)blockIdx.z * K;

    const int srow = wave * 8 + (lane >> 3);
    const int scol = (lane & 7) * 8;
    const bf16* Ag = A + (m0 + srow) * (long)lda + scol + kofs;
    const bf16* Bg = B + (n0 + srow) * (long)lda + scol + kofs;
    bf16* Asw = &As[(wave * 8) * BK];
    bf16* Bsw = &Bs[(wave * 8) * BK];

    f32x4 acc[4][4] = {};
    const int row = lane & 15;
    const int kq  = (lane >> 4) * 8;

    for (int k0 = 0; k0 < K; k0 += BK) {
#pragma unroll
        for (int t = 0; t < 4; t++) {
            gld_lds16(Ag + (long)(t * 32) * lda + k0, Asw + t * 32 * BK);
            gld_lds16(Bg + (long)(t * 32) * lda + k0, Bsw + t * 32 * BK);
        }
        __syncthreads();
#pragma unroll
        for (int kk = 0; kk < BK; kk += 32) {
            bf16x8 af[4], bfr[4];
#pragma unroll
            for (int i = 0; i < 4; i++)
                af[i] = *(const bf16x8*)&As[(wm * 64 + i * 16 + row) * BK + kk + kq];
#pragma unroll
            for (int j = 0; j < 4; j++)
                bfr[j] = *(const bf16x8*)&Bs[(wn * 64 + j * 16 + row) * BK + kk + kq];
#pragma unroll
            for (int i = 0; i < 4; i++)
#pragma unroll
                for (int j = 0; j < 4; j++)
                    acc[i][j] = __builtin_amdgcn_mfma_f32_16x16x32_bf16(af[i], bfr[j], acc[i][j], 0, 0, 0);
        }
        __syncthreads();
    }

    const int quad = lane >> 4;
#pragma unroll
    for (int i = 0; i < 4; i++)
#pragma unroll
        for (int j = 0; j < 4; j++)
#pragma unroll
            for (int r = 0; r < 4; r++) {
                long rr = m0 + wm * 64 + i * 16 + quad * 4 + r;   // C/D: row = quad*4+reg
                long cc = n0 + wn * 64 + j * 16 + (lane & 15);    //      col = lane&15
                float v = acc[i][j][r];
                if (EPI == 0) {
                    ((bf16*)Cout)[rr * N + cc] = __float2bfloat16(v);
                } else if (EPI == 1) {
                    ((float*)Cout)[rr * N + cc] = v + R[rr * N + cc];
                } else {
                    ((float*)Cout)[(long)blockIdx.z * M * N + rr * N + cc] = v;
                }
            }
}

// ---------------- RMSNorm: one block per row, fp32 in -> bf16 out -------------------
__global__ __launch_bounds__(256) void rmsnorm_kernel(const float* __restrict__ x,
                                                      const float* __restrict__ w,
                                                      bf16* __restrict__ out) {
    const int row = blockIdx.x;
    const int tid = threadIdx.x;
    const float* xr = x + (long)row * HIDDENC;
    float4 a = *(const float4*)&xr[tid * 8];
    float4 b = *(const float4*)&xr[tid * 8 + 4];
    float ss = a.x*a.x + a.y*a.y + a.z*a.z + a.w*a.w + b.x*b.x + b.y*b.y + b.z*b.z + b.w*b.w;
#pragma unroll
    for (int d = 1; d < 64; d <<= 1) ss += __shfl_xor(ss, d, 64);
    __shared__ float wsum[4];
    if ((tid & 63) == 0) wsum[tid >> 6] = ss;
    __syncthreads();
    ss = wsum[0] + wsum[1] + wsum[2] + wsum[3];
    float sc = rsqrtf(ss * (1.0f / HIDDENC) + 1e-6f);
    float4 wa = *(const float4*)&w[tid * 8];
    float4 wb = *(const float4*)&w[tid * 8 + 4];
    float vals[8] = {a.x*wa.x, a.y*wa.y, a.z*wa.z, a.w*wa.w,
                     b.x*wb.x, b.y*wb.y, b.z*wb.z, b.w*wb.w};
    union { bf16x8 v; unsigned short u[8]; } pk;
#pragma unroll
    for (int e = 0; e < 8; e++) pk.u[e] = bf_bits(vals[e] * sc);
    *(bf16x8*)&out[(long)row * HIDDENC + tid * 8] = pk.v;
}

// ---------------- fp32 -> bf16 convert (weights) ------------------------------------
__global__ __launch_bounds__(256) void cvt_kernel(const float* __restrict__ in,
                                                  bf16* __restrict__ out, long n) {
    long idx = ((long)blockIdx.x * 256 + threadIdx.x) * 8;
    if (idx >= n) return;
    float4 a = *(const float4*)&in[idx];
    float4 b = *(const float4*)&in[idx + 4];
    float vals[8] = {a.x, a.y, a.z, a.w, b.x, b.y, b.z, b.w};
    union { bf16x8 v; unsigned short u[8]; } pk;
#pragma unroll
    for (int e = 0; e < 8; e++) pk.u[e] = bf_bits(vals[e]);
    *(bf16x8*)&out[idx] = pk.v;
}

// ---------------- RoPE in-place on bf16 [S][rowstride], heads at col h*HD -----------
__global__ __launch_bounds__(256) void rope_kernel(bf16* __restrict__ x,
                                                   const int* __restrict__ pos,
                                                   int nheads, int rowstride) {
    long gid = (long)blockIdx.x * 256 + threadIdx.x;
    int i = gid & 63;
    long t = gid >> 6;
    int h = (int)(t % nheads);
    long s = t / nheads;
    if (s >= SLEN) return;
    float inv = __expf(-(float)i * 0.14391156516779195f);   // ln(10000)/64
    float f = (float)pos[s] * inv;
    float sn, c;
    sincosf(f, &sn, &c);
    bf16* p = x + s * (long)rowstride + h * HD + i;
    float x1 = __bfloat162float(p[0]);
    float x2 = __bfloat162float(p[64]);
    p[0]  = __float2bfloat16(x1 * c - x2 * sn);
    p[64] = __float2bfloat16(x2 * c + x1 * sn);
}

// ---------------- causal flash attention v3 -----------------------------------------
// grid (32 qtiles, 16 heads); qt = 31-bx (heavy first). 4 waves x 16 q-rows, no
// __syncthreads: K and V^T read directly from global (L2-resident), only per-wave P
// goes through LDS (PSTR=68 -> 2 lanes/bank on writes = free).
__global__ __launch_bounds__(256) void flash_attn(const bf16* __restrict__ Q,   // [S][2560]
                                                  const bf16* __restrict__ Kb,  // +2048 col
                                                  const bf16* __restrict__ VT,  // [512][2048]
                                                  bf16* __restrict__ Ctx) {     // [S][2048]
    constexpr int QSTR = 2560, PSTR = 68, BKEY = 64;
    __shared__ bf16 Ps[4][16 * PSTR];               // per-wave P [16 q][64 keys + pad]
    const int qt  = 31 - blockIdx.x;                // heavy tiles dispatched first
    const int h   = blockIdx.y;
    const int kvh = h >> 2;
    const int tid = threadIdx.x;
    const int wave = tid >> 6, lane = tid & 63;
    const int quad = lane >> 4, lrow = lane & 15;
    const int qbase = qt * 64 + wave * 16;

    // resident Q fragments (A-layout: m=lane&15, k=quad*8+e)
    bf16x8 qf[4];
#pragma unroll
    for (int kk = 0; kk < 4; kk++)
        qf[kk] = *(const bf16x8*)&Q[(long)(qbase + lrow) * QSTR + h * HD + kk * 32 + quad * 8];

    f32x4 o[8] = {};
    float mrow[4], lsum[4];
#pragma unroll
    for (int r = 0; r < 4; r++) { mrow[r] = -1e30f; lsum[r] = 0.0f; }

    const int nkt = qt + 1;                         // keys < (qt+1)*64
    const float scale = 0.08838834764831845f;       // 1/sqrt(128)
    const bf16* VTh = VT + (long)(kvh * HD) * SLEN; // this kv-head's V^T [128][2048]
    bf16* Pw = Ps[wave];

    for (int kt = 0; kt < nkt; kt++) {
        // S = Q K^T : K fragments straight from global (B-layout: n=lane&15, k=quad*8+e)
        f32x4 sacc[4] = {};
#pragma unroll
        for (int kk = 0; kk < 4; kk++) {
            bf16x8 kb[4];
#pragma unroll
            for (int j = 0; j < 4; j++)
                kb[j] = *(const bf16x8*)&Kb[(long)(kt * BKEY + j * 16 + lrow) * QSTR + kvh * HD + kk * 32 + quad * 8];
#pragma unroll
            for (int j = 0; j < 4; j++)
                sacc[j] = __builtin_amdgcn_mfma_f32_16x16x32_bf16(qf[kk], kb[j], sacc[j], 0, 0, 0);
        }

        // scale + causal mask (only the diagonal tile kt==qt)
        const bool diag = (kt == qt);
#pragma unroll
        for (int j = 0; j < 4; j++)
#pragma unroll
            for (int r = 0; r < 4; r++) {
                float v = sacc[j][r] * scale;
                if (diag) {
                    int rowg = qbase + quad * 4 + r;
                    int colg = qt * 64 + j * 16 + lrow;
                    if (colg > rowg) v = -1e30f;
                }
                sacc[j][r] = v;
            }

        // online softmax per q-row (row lives on 16 lanes sharing quad)
        float alpha[4];
#pragma unroll
        for (int r = 0; r < 4; r++) {
            float mx = sacc[0][r];
#pragma unroll
            for (int j = 1; j < 4; j++) mx = fmaxf(mx, sacc[j][r]);
#pragma unroll
            for (int d = 1; d < 16; d <<= 1) mx = fmaxf(mx, __shfl_xor(mx, d, 16));
            float mnew = fmaxf(mrow[r], mx);
            float a = __expf(mrow[r] - mnew);
            mrow[r] = mnew;
            alpha[r] = a;
            float rs = 0.0f;
#pragma unroll
            for (int j = 0; j < 4; j++) {
                float p = __expf(sacc[j][r] - mnew);
                sacc[j][r] = p;
                rs += p;
            }
#pragma unroll
            for (int d = 1; d < 16; d <<= 1) rs += __shfl_xor(rs, d, 16);
            lsum[r] = lsum[r] * a + rs;
        }

        // rescale O
#pragma unroll
        for (int dj = 0; dj < 8; dj++)
#pragma unroll
            for (int r = 0; r < 4; r++) o[dj][r] *= alpha[r];

        // P (C-layout) -> per-wave LDS (conflict-free) -> A-operand fragments
#pragma unroll
        for (int j = 0; j < 4; j++)
#pragma unroll
            for (int r = 0; r < 4; r++)
                Pw[(quad * 4 + r) * PSTR + j * 16 + lrow] = __float2bfloat16(sacc[j][r]);
        __asm__ volatile("s_waitcnt lgkmcnt(0)" ::: "memory");   // same-wave write->read

        // O += P V : V^T fragments straight from global (B-layout: n=d, k=key)
#pragma unroll
        for (int kk = 0; kk < 2; kk++) {
            bf16x8 pf = *(const bf16x8*)&Pw[lrow * PSTR + kk * 32 + quad * 8];
#pragma unroll
            for (int dj = 0; dj < 8; dj++) {
                bf16x8 vb = *(const bf16x8*)&VTh[(long)(dj * 16 + lrow) * SLEN + kt * BKEY + kk * 32 + quad * 8];
                o[dj] = __builtin_amdgcn_mfma_f32_16x16x32_bf16(pf, vb, o[dj], 0, 0, 0);
            }
        }
    }

    // epilogue: ctx[s][h*128 + d] = O / lsum
#pragma unroll
    for (int dj = 0; dj < 8; dj++)
#pragma unroll
        for (int r = 0; r < 4; r++) {
            long rowg = qbase + quad * 4 + r;
            long col  = (long)h * HD + dj * 16 + lrow;
            Ctx[rowg * (NHEADS * HD) + col] = __float2bfloat16(o[dj][r] / lsum[r]);
        }
}

// ---------------- SwiGLU elementwise: act = silu(gate) * up (bf16) ------------------
__global__ __launch_bounds__(256) void silu_mul_kernel(const bf16* __restrict__ g,
                                                       const bf16* __restrict__ u,
                                                       bf16* __restrict__ out, long n) {
    long idx = ((long)blockIdx.x * 256 + threadIdx.x) * 8;
    if (idx >= n) return;
    bf16x8 gv = *(const bf16x8*)&g[idx];
    bf16x8 uv = *(const bf16x8*)&u[idx];
    union { bf16x8 v; unsigned short w[8]; } pk;
#pragma unroll
    for (int e = 0; e < 8; e++) {
        float gf = bits_f(gv[e]);
        float uf = bits_f(uv[e]);
        float s = gf / (1.0f + __expf(-gf));
        pk.w[e] = bf_bits(s * uf);
    }
    *(bf16x8*)&out[idx] = pk.v;
}

// ---------------- split-K reduce: out += p0 + p1 (residual already in out) ----------
__global__ __launch_bounds__(256) void reduce2_kernel(const float* __restrict__ p,
                                                      float* __restrict__ out, long n) {
    long idx = ((long)blockIdx.x * 256 + threadIdx.x) * 4;
    if (idx >= n) return;
    float4 a = *(const float4*)&p[idx];
    float4 b = *(const float4*)&p[idx + n];
    float4 o = *(const float4*)&out[idx];
    o.x += a.x + b.x; o.y += a.y + b.y; o.z += a.z + b.z; o.w += a.w + b.w;
    *(float4*)&out[idx] = o;
}

// ------------------------------------------------------------------------------------
extern "C" void kernel_launch(void* const* d_in, const int* in_sizes, int n_in,
                              void* d_out, int out_size, void* d_ws, size_t ws_size,
                              hipStream_t stream) {
    const float* hidden = (const float*)d_in[0];
    const int*   pos    = (const int*)d_in[2];
    const float* n1w    = (const float*)d_in[3];
    const float* n2w    = (const float*)d_in[4];
    const float* Wq     = (const float*)d_in[5];
    const float* Wk     = (const float*)d_in[6];
    const float* Wv     = (const float*)d_in[7];
    const float* Wo     = (const float*)d_in[8];
    const float* Wg     = (const float*)d_in[9];
    const float* Wu     = (const float*)d_in[10];
    const float* Wd     = (const float*)d_in[11];
    float* out = (float*)d_out;

    char* ws = (char*)d_ws;
    const size_t MB = 1ull << 20;
    // Phase A:
    bf16* h    = (bf16*)(ws + 0);        // 8 MB  (also h2)
    bf16* qk   = (bf16*)(ws + 8  * MB);  // 10 MB [2048][2560] = q|k
    bf16* vt   = (bf16*)(ws + 18 * MB);  // 2 MB  [512][2048]  = V^T
    bf16* ctx  = (bf16*)(ws + 20 * MB);  // 8 MB
    bf16* wqk  = (bf16*)(ws + 28 * MB);  // 10 MB [2560][2048]; reused for wob (8 MB)
    bf16* wvb  = (bf16*)(ws + 38 * MB);  // 2 MB  [512][2048]
    // Phase B (reuses phase-A space once dead):
    bf16*  wg   = (bf16*)(ws + 8   * MB); // 32 MB
    bf16*  wu   = (bf16*)(ws + 40  * MB); // 32 MB
    bf16*  gate = (bf16*)(ws + 72  * MB); // 32 MB (silu writes act in-place)
    bf16*  up   = (bf16*)(ws + 104 * MB); // 32 MB
    bf16*  wd   = (bf16*)(ws + 104 * MB); // 32 MB (reuses up after silu)
    float* pbuf = (float*)(ws + 28 * MB); // 32 MB (2 x 16 MB split-K partials; wg/wu dead)
    bf16* wob = wqk;

    // 1) rmsnorm1 -> h
    rmsnorm_kernel<<<dim3(2048), dim3(256), 0, stream>>>(hidden, n1w, h);
    // 2) convert Wq|Wk into [2560][2048], Wv into its own block
    cvt_kernel<<<dim3(2048), dim3(256), 0, stream>>>(Wq, wqk,                2048L * 2048);
    cvt_kernel<<<dim3(512),  dim3(256), 0, stream>>>(Wk, wqk + 2048L * 2048, 512L * 2048);
    cvt_kernel<<<dim3(512),  dim3(256), 0, stream>>>(Wv, wvb,                512L * 2048);
    // 3) fused QK projection -> qk [2048][2560];  V^T = Wv @ h^T -> vt [512][2048]
    gemm_bt<0><<<dim3(20, 16), dim3(256), 0, stream>>>(h, wqk, qk, nullptr, 2048, 2560, 2048, 2048);
    gemm_bt<0><<<dim3(16, 4),  dim3(256), 0, stream>>>(wvb, h, vt, nullptr, 512, 2048, 2048, 2048);
    // 4) rope on q (cols 0..2047) and k (cols 2048..2559)
    rope_kernel<<<dim3(8192), dim3(256), 0, stream>>>(qk, pos, NHEADS, 2560);
    rope_kernel<<<dim3(2048), dim3(256), 0, stream>>>(qk + 2048, pos, NKV, 2560);
    // 5) flash attention -> ctx
    flash_attn<<<dim3(32, 16), dim3(256), 0, stream>>>(qk, qk + 2048, vt, ctx);
    // 6) Wo projection + residual -> out (fp32)
    cvt_kernel<<<dim3(2048), dim3(256), 0, stream>>>(Wo, wob, 2048L * 2048);
    gemm_bt<1><<<dim3(16, 16), dim3(256), 0, stream>>>(ctx, wob, out, hidden, 2048, 2048, 2048, 2048);
    // 7) rmsnorm2 -> h
    rmsnorm_kernel<<<dim3(2048), dim3(256), 0, stream>>>(out, n2w, h);
    // 8) MLP
    cvt_kernel<<<dim3(8192), dim3(256), 0, stream>>>(Wg, wg, 8192L * 2048);
    cvt_kernel<<<dim3(8192), dim3(256), 0, stream>>>(Wu, wu, 8192L * 2048);
    gemm_bt<0><<<dim3(64, 16), dim3(256), 0, stream>>>(h, wg, gate, nullptr, 2048, 8192, 2048, 2048);
    gemm_bt<0><<<dim3(64, 16), dim3(256), 0, stream>>>(h, wu, up,   nullptr, 2048, 8192, 2048, 2048);
    silu_mul_kernel<<<dim3(8192), dim3(256), 0, stream>>>(gate, up, gate, 2048L * 8192);
    cvt_kernel<<<dim3(8192), dim3(256), 0, stream>>>(Wd, wd, 2048L * 8192);
    // 9) down-proj split-K=2 -> partials, then out += p0 + p1 (out holds residual x)
    gemm_bt<2><<<dim3(16, 16, 2), dim3(256), 0, stream>>>(gate, wd, pbuf, nullptr, 2048, 2048, 4096, 8192);
    reduce2_kernel<<<dim3(4096), dim3(256), 0, stream>>>(pbuf, out, 2048L * 2048);
    (void)in_sizes; (void)n_in; (void)out_size; (void)ws_size;
}

// Round 4
// 842.748 us; speedup vs baseline: 1.1937x; 1.1937x over previous
//
#include <hip/hip_runtime.h>
#include <hip/hip_bf16.h>
#include <math.h>

// Transformer block: rmsnorm -> fused QK GEMM + V^T GEMM -> rope -> causal flash attn
// (v4: cooperative XOR-swizzled LDS staging of K and V^T, conflict-free) -> Wo +
// residual -> rmsnorm -> SwiGLU MLP -> split-K down-proj + residual.

#define HIDDENC 2048
#define SLEN    2048
#define NHEADS  16
#define NKV     4
#define HD      128
#define INTERC  8192

typedef __attribute__((ext_vector_type(8))) short bf16x8;   // 8 x bf16 (4 VGPRs)
typedef __attribute__((ext_vector_type(4))) float f32x4;
typedef __hip_bfloat16 bf16;

__device__ __forceinline__ void gld_lds16(const void* g, void* l) {
    __builtin_amdgcn_global_load_lds((const __attribute__((address_space(1))) void*)g,
                                     (__attribute__((address_space(3))) void*)l, 16, 0, 0);
}

__device__ __forceinline__ unsigned short bf_bits(float x) {
    bf16 t = __float2bfloat16(x);
    return *(unsigned short*)&t;
}
__device__ __forceinline__ float bits_f(short s) {
    bf16 b = *(bf16*)&s;
    return __bfloat162float(b);
}

// ---------------- GEMM: C[M][N] = A[M][K'] @ B[N][K']^T, row stride lda -------------
// EPI=0: bf16 C.  EPI=1: fp32 C = acc + R.  EPI=2: fp32 partial at Cout + z*M*N.
template <int EPI>
__global__ __launch_bounds__(256) void gemm_bt(const bf16* __restrict__ A,
                                               const bf16* __restrict__ B,
                                               void* __restrict__ Cout,
                                               const float* __restrict__ R,
                                               int M, int N, int K, int lda) {
    constexpr int BM = 128, BN = 128, BK = 64;
    __shared__ bf16 As[BM * BK];
    __shared__ bf16 Bs[BN * BK];
    const int tid  = threadIdx.x;
    const int wave = tid >> 6;
    const int lane = tid & 63;
    const int wm = wave >> 1, wn = wave & 1;        // 2x2 waves, 64x64 each
    const long m0 = (long)blockIdx.y * BM;
    const long n0 = (long)blockIdx.x * BN;
    const long kofs = (long)blockIdx.z * K;

    const int srow = wave * 8 + (lane >> 3);
    const int scol = (lane & 7) * 8;
    const bf16* Ag = A + (m0 + srow) * (long)lda + scol + kofs;
    const bf16* Bg = B + (n0 + srow) * (long)lda + scol + kofs;
    bf16* Asw = &As[(wave * 8) * BK];
    bf16* Bsw = &Bs[(wave * 8) * BK];

    f32x4 acc[4][4] = {};
    const int row = lane & 15;
    const int kq  = (lane >> 4) * 8;

    for (int k0 = 0; k0 < K; k0 += BK) {
#pragma unroll
        for (int t = 0; t < 4; t++) {
            gld_lds16(Ag + (long)(t * 32) * lda + k0, Asw + t * 32 * BK);
            gld_lds16(Bg + (long)(t * 32) * lda + k0, Bsw + t * 32 * BK);
        }
        __syncthreads();
#pragma unroll
        for (int kk = 0; kk < BK; kk += 32) {
            bf16x8 af[4], bfr[4];
#pragma unroll
            for (int i = 0; i < 4; i++)
                af[i] = *(const bf16x8*)&As[(wm * 64 + i * 16 + row) * BK + kk + kq];
#pragma unroll
            for (int j = 0; j < 4; j++)
                bfr[j] = *(const bf16x8*)&Bs[(wn * 64 + j * 16 + row) * BK + kk + kq];
#pragma unroll
            for (int i = 0; i < 4; i++)
#pragma unroll
                for (int j = 0; j < 4; j++)
                    acc[i][j] = __builtin_amdgcn_mfma_f32_16x16x32_bf16(af[i], bfr[j], acc[i][j], 0, 0, 0);
        }
        __syncthreads();
    }

    const int quad = lane >> 4;
#pragma unroll
    for (int i = 0; i < 4; i++)
#pragma unroll
        for (int j = 0; j < 4; j++)
#pragma unroll
            for (int r = 0; r < 4; r++) {
                long rr = m0 + wm * 64 + i * 16 + quad * 4 + r;   // C/D: row = quad*4+reg
                long cc = n0 + wn * 64 + j * 16 + (lane & 15);    //      col = lane&15
                float v = acc[i][j][r];
                if (EPI == 0) {
                    ((bf16*)Cout)[rr * N + cc] = __float2bfloat16(v);
                } else if (EPI == 1) {
                    ((float*)Cout)[rr * N + cc] = v + R[rr * N + cc];
                } else {
                    ((float*)Cout)[(long)blockIdx.z * M * N + rr * N + cc] = v;
                }
            }
}

// ---------------- RMSNorm: one block per row, fp32 in -> bf16 out -------------------
__global__ __launch_bounds__(256) void rmsnorm_kernel(const float* __restrict__ x,
                                                      const float* __restrict__ w,
                                                      bf16* __restrict__ out) {
    const int row = blockIdx.x;
    const int tid = threadIdx.x;
    const float* xr = x + (long)row * HIDDENC;
    float4 a = *(const float4*)&xr[tid * 8];
    float4 b = *(const float4*)&xr[tid * 8 + 4];
    float ss = a.x*a.x + a.y*a.y + a.z*a.z + a.w*a.w + b.x*b.x + b.y*b.y + b.z*b.z + b.w*b.w;
#pragma unroll
    for (int d = 1; d < 64; d <<= 1) ss += __shfl_xor(ss, d, 64);
    __shared__ float wsum[4];
    if ((tid & 63) == 0) wsum[tid >> 6] = ss;
    __syncthreads();
    ss = wsum[0] + wsum[1] + wsum[2] + wsum[3];
    float sc = rsqrtf(ss * (1.0f / HIDDENC) + 1e-6f);
    float4 wa = *(const float4*)&w[tid * 8];
    float4 wb = *(const float4*)&w[tid * 8 + 4];
    float vals[8] = {a.x*wa.x, a.y*wa.y, a.z*wa.z, a.w*wa.w,
                     b.x*wb.x, b.y*wb.y, b.z*wb.z, b.w*wb.w};
    union { bf16x8 v; unsigned short u[8]; } pk;
#pragma unroll
    for (int e = 0; e < 8; e++) pk.u[e] = bf_bits(vals[e] * sc);
    *(bf16x8*)&out[(long)row * HIDDENC + tid * 8] = pk.v;
}

// ---------------- fp32 -> bf16 convert (weights) ------------------------------------
__global__ __launch_bounds__(256) void cvt_kernel(const float* __restrict__ in,
                                                  bf16* __restrict__ out, long n) {
    long idx = ((long)blockIdx.x * 256 + threadIdx.x) * 8;
    if (idx >= n) return;
    float4 a = *(const float4*)&in[idx];
    float4 b = *(const float4*)&in[idx + 4];
    float vals[8] = {a.x, a.y, a.z, a.w, b.x, b.y, b.z, b.w};
    union { bf16x8 v; unsigned short u[8]; } pk;
#pragma unroll
    for (int e = 0; e < 8; e++) pk.u[e] = bf_bits(vals[e]);
    *(bf16x8*)&out[idx] = pk.v;
}

// ---------------- RoPE in-place on bf16 [S][rowstride], heads at col h*HD -----------
__global__ __launch_bounds__(256) void rope_kernel(bf16* __restrict__ x,
                                                   const int* __restrict__ pos,
                                                   int nheads, int rowstride) {
    long gid = (long)blockIdx.x * 256 + threadIdx.x;
    int i = gid & 63;
    long t = gid >> 6;
    int h = (int)(t % nheads);
    long s = t / nheads;
    if (s >= SLEN) return;
    float inv = __expf(-(float)i * 0.14391156516779195f);   // ln(10000)/64
    float f = (float)pos[s] * inv;
    float sn, c;
    sincosf(f, &sn, &c);
    bf16* p = x + s * (long)rowstride + h * HD + i;
    float x1 = __bfloat162float(p[0]);
    float x2 = __bfloat162float(p[64]);
    p[0]  = __float2bfloat16(x1 * c - x2 * sn);
    p[64] = __float2bfloat16(x2 * c + x1 * sn);
}

// ---------------- causal flash attention v4 -----------------------------------------
// grid (32 qtiles, 16 heads) = 512 blocks; qt = 31-bx (heavy first). 4 waves x 16
// q-rows. Per kt: cooperative stage of K tile [64][128] and V^T tile [128][64] into
// LDS with XOR-swizzled 16B granules (conflict-free writes AND fragment reads).
__global__ __launch_bounds__(256) void flash_attn(const bf16* __restrict__ Q,   // [S][2560]
                                                  const bf16* __restrict__ Kb,  // +2048 col
                                                  const bf16* __restrict__ VT,  // [512][2048]
                                                  bf16* __restrict__ Ctx) {     // [S][2048]
    constexpr int QSTR = 2560, PSTR = 68, BKEY = 64;
    __shared__ bf16 Ks[64 * 128];                   // swizzled [key][d], 16 KB
    __shared__ bf16 Vs[128 * 64];                   // swizzled [d][key], 16 KB
    __shared__ bf16 Ps[4][16 * PSTR];               // per-wave P [16 q][64 keys + pad]
    const int qt  = 31 - blockIdx.x;                // heavy tiles dispatched first
    const int h   = blockIdx.y;
    const int kvh = h >> 2;
    const int tid = threadIdx.x;
    const int wave = tid >> 6, lane = tid & 63;
    const int quad = lane >> 4, lrow = lane & 15;
    const int qbase = qt * 64 + wave * 16;

    // resident Q fragments (A-layout: m=lane&15, k=quad*8+e)
    bf16x8 qf[4];
#pragma unroll
    for (int kk = 0; kk < 4; kk++)
        qf[kk] = *(const bf16x8*)&Q[(long)(qbase + lrow) * QSTR + h * HD + kk * 32 + quad * 8];

    f32x4 o[8] = {};
    float mrow[4], lsum[4];
#pragma unroll
    for (int r = 0; r < 4; r++) { mrow[r] = -1e30f; lsum[r] = 0.0f; }

    const int nkt = qt + 1;                         // keys < (qt+1)*64
    const float scale = 0.08838834764831845f;       // 1/sqrt(128)
    const bf16* Kh  = Kb + kvh * HD;                // [key][2560]
    const bf16* VTh = VT + (long)(kvh * HD) * SLEN; // [128][2048]
    bf16* Pw = Ps[wave];

    for (int kt = 0; kt < nkt; kt++) {
        __syncthreads();                            // guard Ks/Vs reuse
        // stage K tile [64 keys][128 d]: granule g (16B) -> g ^ (row & 15)
#pragma unroll
        for (int rd = 0; rd < 4; rd++) {
            int id = rd * 256 + tid;
            int row = id >> 4, g = id & 15;
            bf16x8 kv = *(const bf16x8*)&Kh[(long)(kt * BKEY + row) * QSTR + g * 8];
            *(bf16x8*)&Ks[row * 128 + ((g ^ (row & 15)) * 8)] = kv;
        }
        // stage V^T tile [128 d][64 keys]: granule g (16B) -> g ^ (d & 7)
#pragma unroll
        for (int rd = 0; rd < 4; rd++) {
            int id = rd * 256 + tid;
            int d = id >> 3, g = id & 7;
            bf16x8 vv = *(const bf16x8*)&VTh[(long)d * SLEN + kt * BKEY + g * 8];
            *(bf16x8*)&Vs[d * 64 + ((g ^ (d & 7)) * 8)] = vv;
        }
        __syncthreads();

        // S = Q K^T : K fragments from swizzled LDS (B-layout: n=key on lanes)
        f32x4 sacc[4] = {};
#pragma unroll
        for (int kk = 0; kk < 4; kk++) {
            bf16x8 kb[4];
#pragma unroll
            for (int j = 0; j < 4; j++)
                kb[j] = *(const bf16x8*)&Ks[(j * 16 + lrow) * 128 + (((kk * 4 + quad) ^ lrow) * 8)];
#pragma unroll
            for (int j = 0; j < 4; j++)
                sacc[j] = __builtin_amdgcn_mfma_f32_16x16x32_bf16(qf[kk], kb[j], sacc[j], 0, 0, 0);
        }

        // scale + causal mask (only the diagonal tile kt==qt)
        const bool diag = (kt == qt);
#pragma unroll
        for (int j = 0; j < 4; j++)
#pragma unroll
            for (int r = 0; r < 4; r++) {
                float v = sacc[j][r] * scale;
                if (diag) {
                    int rowg = qbase + quad * 4 + r;
                    int colg = qt * 64 + j * 16 + lrow;
                    if (colg > rowg) v = -1e30f;
                }
                sacc[j][r] = v;
            }

        // online softmax per q-row (row lives on 16 lanes sharing quad)
        float alpha[4];
#pragma unroll
        for (int r = 0; r < 4; r++) {
            float mx = sacc[0][r];
#pragma unroll
            for (int j = 1; j < 4; j++) mx = fmaxf(mx, sacc[j][r]);
#pragma unroll
            for (int d = 1; d < 16; d <<= 1) mx = fmaxf(mx, __shfl_xor(mx, d, 16));
            float mnew = fmaxf(mrow[r], mx);
            float a = __expf(mrow[r] - mnew);
            mrow[r] = mnew;
            alpha[r] = a;
            float rs = 0.0f;
#pragma unroll
            for (int j = 0; j < 4; j++) {
                float p = __expf(sacc[j][r] - mnew);
                sacc[j][r] = p;
                rs += p;
            }
#pragma unroll
            for (int d = 1; d < 16; d <<= 1) rs += __shfl_xor(rs, d, 16);
            lsum[r] = lsum[r] * a + rs;
        }

        // rescale O
#pragma unroll
        for (int dj = 0; dj < 8; dj++)
#pragma unroll
            for (int r = 0; r < 4; r++) o[dj][r] *= alpha[r];

        // P (C-layout) -> per-wave LDS (conflict-free) -> A-operand fragments
#pragma unroll
        for (int j = 0; j < 4; j++)
#pragma unroll
            for (int r = 0; r < 4; r++)
                Pw[(quad * 4 + r) * PSTR + j * 16 + lrow] = __float2bfloat16(sacc[j][r]);
        __asm__ volatile("s_waitcnt lgkmcnt(0)" ::: "memory");   // same-wave write->read

        // O += P V : V^T fragments from swizzled LDS (B-layout: n=d on lanes)
#pragma unroll
        for (int kk = 0; kk < 2; kk++) {
            bf16x8 pf = *(const bf16x8*)&Pw[lrow * PSTR + kk * 32 + quad * 8];
#pragma unroll
            for (int dj = 0; dj < 8; dj++) {
                int dr = dj * 16 + lrow;
                bf16x8 vb = *(const bf16x8*)&Vs[dr * 64 + (((kk * 4 + quad) ^ (dr & 7)) * 8)];
                o[dj] = __builtin_amdgcn_mfma_f32_16x16x32_bf16(pf, vb, o[dj], 0, 0, 0);
            }
        }
    }

    // epilogue: ctx[s][h*128 + d] = O / lsum
#pragma unroll
    for (int dj = 0; dj < 8; dj++)
#pragma unroll
        for (int r = 0; r < 4; r++) {
            long rowg = qbase + quad * 4 + r;
            long col  = (long)h * HD + dj * 16 + lrow;
            Ctx[rowg * (NHEADS * HD) + col] = __float2bfloat16(o[dj][r] / lsum[r]);
        }
}

// ---------------- SwiGLU elementwise: act = silu(gate) * up (bf16) ------------------
__global__ __launch_bounds__(256) void silu_mul_kernel(const bf16* __restrict__ g,
                                                       const bf16* __restrict__ u,
                                                       bf16* __restrict__ out, long n) {
    long idx = ((long)blockIdx.x * 256 + threadIdx.x) * 8;
    if (idx >= n) return;
    bf16x8 gv = *(const bf16x8*)&g[idx];
    bf16x8 uv = *(const bf16x8*)&u[idx];
    union { bf16x8 v; unsigned short w[8]; } pk;
#pragma unroll
    for (int e = 0; e < 8; e++) {
        float gf = bits_f(gv[e]);
        float uf = bits_f(uv[e]);
        float s = gf / (1.0f + __expf(-gf));
        pk.w[e] = bf_bits(s * uf);
    }
    *(bf16x8*)&out[idx] = pk.v;
}

// ---------------- split-K reduce: out += p0 + p1 (residual already in out) ----------
__global__ __launch_bounds__(256) void reduce2_kernel(const float* __restrict__ p,
                                                      float* __restrict__ out, long n) {
    long idx = ((long)blockIdx.x * 256 + threadIdx.x) * 4;
    if (idx >= n) return;
    float4 a = *(const float4*)&p[idx];
    float4 b = *(const float4*)&p[idx + n];
    float4 o = *(const float4*)&out[idx];
    o.x += a.x + b.x; o.y += a.y + b.y; o.z += a.z + b.z; o.w += a.w + b.w;
    *(float4*)&out[idx] = o;
}

// ------------------------------------------------------------------------------------
extern "C" void kernel_launch(void* const* d_in, const int* in_sizes, int n_in,
                              void* d_out, int out_size, void* d_ws, size_t ws_size,
                              hipStream_t stream) {
    const float* hidden = (const float*)d_in[0];
    const int*   pos    = (const int*)d_in[2];
    const float* n1w    = (const float*)d_in[3];
    const float* n2w    = (const float*)d_in[4];
    const float* Wq     = (const float*)d_in[5];
    const float* Wk     = (const float*)d_in[6];
    const float* Wv     = (const float*)d_in[7];
    const float* Wo     = (const float*)d_in[8];
    const float* Wg     = (const float*)d_in[9];
    const float* Wu     = (const float*)d_in[10];
    const float* Wd     = (const float*)d_in[11];
    float* out = (float*)d_out;

    char* ws = (char*)d_ws;
    const size_t MB = 1ull << 20;
    // Phase A:
    bf16* h    = (bf16*)(ws + 0);        // 8 MB  (also h2)
    bf16* qk   = (bf16*)(ws + 8  * MB);  // 10 MB [2048][2560] = q|k
    bf16* vt   = (bf16*)(ws + 18 * MB);  // 2 MB  [512][2048]  = V^T
    bf16* ctx  = (bf16*)(ws + 20 * MB);  // 8 MB
    bf16* wqk  = (bf16*)(ws + 28 * MB);  // 10 MB [2560][2048]; reused for wob (8 MB)
    bf16* wvb  = (bf16*)(ws + 38 * MB);  // 2 MB  [512][2048]
    // Phase B (reuses phase-A space once dead):
    bf16*  wg   = (bf16*)(ws + 8   * MB); // 32 MB
    bf16*  wu   = (bf16*)(ws + 40  * MB); // 32 MB
    bf16*  gate = (bf16*)(ws + 72  * MB); // 32 MB (silu writes act in-place)
    bf16*  up   = (bf16*)(ws + 104 * MB); // 32 MB
    bf16*  wd   = (bf16*)(ws + 104 * MB); // 32 MB (reuses up after silu)
    float* pbuf = (float*)(ws + 28 * MB); // 32 MB (2 x 16 MB split-K partials; wg/wu dead)
    bf16* wob = wqk;

    // 1) rmsnorm1 -> h
    rmsnorm_kernel<<<dim3(2048), dim3(256), 0, stream>>>(hidden, n1w, h);
    // 2) convert Wq|Wk into [2560][2048], Wv into its own block
    cvt_kernel<<<dim3(2048), dim3(256), 0, stream>>>(Wq, wqk,                2048L * 2048);
    cvt_kernel<<<dim3(512),  dim3(256), 0, stream>>>(Wk, wqk + 2048L * 2048, 512L * 2048);
    cvt_kernel<<<dim3(512),  dim3(256), 0, stream>>>(Wv, wvb,                512L * 2048);
    // 3) fused QK projection -> qk [2048][2560];  V^T = Wv @ h^T -> vt [512][2048]
    gemm_bt<0><<<dim3(20, 16), dim3(256), 0, stream>>>(h, wqk, qk, nullptr, 2048, 2560, 2048, 2048);
    gemm_bt<0><<<dim3(16, 4),  dim3(256), 0, stream>>>(wvb, h, vt, nullptr, 512, 2048, 2048, 2048);
    // 4) rope on q (cols 0..2047) and k (cols 2048..2559)
    rope_kernel<<<dim3(8192), dim3(256), 0, stream>>>(qk, pos, NHEADS, 2560);
    rope_kernel<<<dim3(2048), dim3(256), 0, stream>>>(qk + 2048, pos, NKV, 2560);
    // 5) flash attention -> ctx
    flash_attn<<<dim3(32, 16), dim3(256), 0, stream>>>(qk, qk + 2048, vt, ctx);
    // 6) Wo projection + residual -> out (fp32)
    cvt_kernel<<<dim3(2048), dim3(256), 0, stream>>>(Wo, wob, 2048L * 2048);
    gemm_bt<1><<<dim3(16, 16), dim3(256), 0, stream>>>(ctx, wob, out, hidden, 2048, 2048, 2048, 2048);
    // 7) rmsnorm2 -> h
    rmsnorm_kernel<<<dim3(2048), dim3(256), 0, stream>>>(out, n2w, h);
    // 8) MLP
    cvt_kernel<<<dim3(8192), dim3(256), 0, stream>>>(Wg, wg, 8192L * 2048);
    cvt_kernel<<<dim3(8192), dim3(256), 0, stream>>>(Wu, wu, 8192L * 2048);
    gemm_bt<0><<<dim3(64, 16), dim3(256), 0, stream>>>(h, wg, gate, nullptr, 2048, 8192, 2048, 2048);
    gemm_bt<0><<<dim3(64, 16), dim3(256), 0, stream>>>(h, wu, up,   nullptr, 2048, 8192, 2048, 2048);
    silu_mul_kernel<<<dim3(8192), dim3(256), 0, stream>>>(gate, up, gate, 2048L * 8192);
    cvt_kernel<<<dim3(8192), dim3(256), 0, stream>>>(Wd, wd, 2048L * 8192);
    // 9) down-proj split-K=2 -> partials, then out += p0 + p1 (out holds residual x)
    gemm_bt<2><<<dim3(16, 16, 2), dim3(256), 0, stream>>>(gate, wd, pbuf, nullptr, 2048, 2048, 4096, 8192);
    reduce2_kernel<<<dim3(4096), dim3(256), 0, stream>>>(pbuf, out, 2048L * 2048);
    (void)in_sizes; (void)n_in; (void)out_size; (void)ws_size;
}